// Round 13
// baseline (187.873 us; speedup 1.0000x reference)
//
#include <hip/hip_runtime.h>
#include <hip/hip_bf16.h>

typedef __hip_bfloat16 bf16;
typedef short bf16x8 __attribute__((ext_vector_type(8)));
typedef short bf16x4 __attribute__((ext_vector_type(4)));
typedef float floatx4 __attribute__((ext_vector_type(4)));

#define Bb 2
#define Ll 2048
#define Cc 1024
#define Hh 16
#define Dd 64
// ln(50000)/32
#define INVFREQ_LN 0.3381180763f
// plain 1/sqrt(D) folded into Q; softmax uses __expf (natural)
#define QSCALE 0.125f
#define NCONV 4096

#define GLD16(gp, lp) __builtin_amdgcn_global_load_lds( \
    (const __attribute__((address_space(1))) void*)(gp), \
    (__attribute__((address_space(3))) void*)(lp), 16, 0, 0)

__device__ inline short f2bf(float f) {
    __hip_bfloat16 h = __float2bfloat16(f);
    return *reinterpret_cast<short*>(&h);
}
// fast round-to-nearest bf16; fine for finite values
__device__ inline short f2bf_rn(float f) {
    return (short)((__float_as_uint(f) + 0x8000u) >> 16);
}

// ---------------- convert fp32 -> bf16 workspace + fused per-batch mask scan ----------------
__global__ __launch_bounds__(256) void convert_scan(
    const float* __restrict__ x, const float* __restrict__ wq,
    const float* __restrict__ wk, const float* __restrict__ wv,
    const float* __restrict__ wo,
    bf16* __restrict__ xb, bf16* __restrict__ wqkv, bf16* __restrict__ wob,
    const int* __restrict__ mask, int* __restrict__ cidx, int* __restrict__ valid)
{
    if (blockIdx.x >= NCONV) {
        // ---- mask scan for batch b ----
        const int b   = blockIdx.x - NCONV;
        const int tid = threadIdx.x;
        const int base = b * Ll + tid * 8;
        int m[8]; int s = 0;
        #pragma unroll
        for (int i = 0; i < 8; i++) { m[i] = mask[base + i] ? 1 : 0; s += m[i]; }
        const int lane = tid & 63;
        int xx = s;
        #pragma unroll
        for (int off = 1; off < 64; off <<= 1) {
            int y = __shfl_up(xx, off);
            if (lane >= off) xx += y;
        }
        __shared__ int wtot[4];
        if (lane == 63) wtot[tid >> 6] = xx;
        __syncthreads();
        int wbase = 0;
        const int w = tid >> 6;
        #pragma unroll
        for (int i = 0; i < 4; i++) if (i < w) wbase += wtot[i];
        int run = wbase + (xx - s);
        #pragma unroll
        for (int i = 0; i < 8; i++) { cidx[base + i] = run; run += m[i]; }
        if (tid == 255) valid[b] = run;
        return;
    }

    const int XN = (Bb * Ll * Cc) / 8;   // 524288
    const int WN = (Cc * Cc) / 8;        // 131072
    int i = blockIdx.x * 256 + threadIdx.x;
    const float* src; bf16* dst;
    if (i < XN)               { src = x  + (size_t)i * 8;                 dst = xb   + (size_t)i * 8; }
    else if (i < XN + WN)     { int j = i - XN;        src = wq + (size_t)j * 8; dst = wqkv + (size_t)j * 8; }
    else if (i < XN + 2*WN)   { int j = i - XN - WN;   src = wk + (size_t)j * 8; dst = wqkv + (size_t)Cc*Cc     + (size_t)j * 8; }
    else if (i < XN + 3*WN)   { int j = i - XN - 2*WN; src = wv + (size_t)j * 8; dst = wqkv + (size_t)Cc*Cc*2   + (size_t)j * 8; }
    else                      { int j = i - XN - 3*WN; src = wo + (size_t)j * 8; dst = wob  + (size_t)j * 8; }
    float4 a = *reinterpret_cast<const float4*>(src);
    float4 b = *reinterpret_cast<const float4*>(src + 4);
    float vv[8] = {a.x, a.y, a.z, a.w, b.x, b.y, b.z, b.w};
    bf16x8 o;
    #pragma unroll
    for (int t = 0; t < 8; t++) o[t] = f2bf(vv[t]);
    *reinterpret_cast<bf16x8*>(dst) = o;
}

// ---------------- MFMA GEMM: C = A[M,K] . W[N,K]^T, all bf16, dbuf K-loop ----------------
// Block = 256 threads = 4 waves (2x2). Wave tile = (WMT*16) x 64; block = (WMT*32) x 128.
// MODE 0 (WMT=8): N=3072 fused QKV. Epilogue: RoPE+scale on q (linear layout);
//         K/V written COMPACTED by cidx, K XOR-swizzled; V transposed+swizzled.
// MODE 1 (WMT=4): N=1024, out fp32 [M,N] + bias
template <int MODE, int WMT>
__global__ __launch_bounds__(256, 2) void gemm_mfma(
    const bf16* __restrict__ A, const bf16* __restrict__ W,
    bf16* __restrict__ qb, bf16* __restrict__ kb, bf16* __restrict__ vb,
    float* __restrict__ outf, const float* __restrict__ bias,
    const int* __restrict__ cmask, const int* __restrict__ cidx,
    int M, int N, int K)
{
    const int RM = WMT * 32;                 // block rows
    __shared__ __align__(16) short As[2][WMT * 1024];   // RM x 32
    __shared__ __align__(16) short Bs[2][128 * 32];

    const int tid  = threadIdx.x;
    const int wave = tid >> 6;
    const int lane = tid & 63;
    const int l15  = lane & 15;
    const int quad = lane >> 4;
    const int wm   = wave >> 1;       // 2x2 wave grid
    const int wn   = wave & 1;
    const int m0   = blockIdx.y * RM;
    const int n0   = blockIdx.x * 128;

    const int ar = tid >> 2;          // 0..63 (row within 64-row chunk)
    const int ac = (tid & 3) * 8;     // 0,8,16,24

    floatx4 acc[WMT][4];
    #pragma unroll
    for (int mt = 0; mt < WMT; mt++)
        #pragma unroll
        for (int nt = 0; nt < 4; nt++)
            #pragma unroll
            for (int r = 0; r < 4; r++) acc[mt][nt][r] = 0.f;

    // prologue: stage k0=0 into buffer 0
    #pragma unroll
    for (int p = 0; p < RM / 64; p++)
        GLD16(A + (size_t)(m0 + p * 64 + ar) * K + ac, &As[0][(p * 64 + ar) * 32 + ac]);
    #pragma unroll
    for (int p = 0; p < 2; p++)
        GLD16(W + (size_t)(n0 + p * 64 + ar) * K + ac, &Bs[0][(p * 64 + ar) * 32 + ac]);

    for (int k0 = 0; k0 < K; k0 += 32) {
        const int cur = (k0 >> 5) & 1;
        __syncthreads();   // drains this tile's GLDs
        if (k0 + 32 < K) {
            #pragma unroll
            for (int p = 0; p < RM / 64; p++)
                GLD16(A + (size_t)(m0 + p * 64 + ar) * K + k0 + 32 + ac,
                      &As[cur ^ 1][(p * 64 + ar) * 32 + ac]);
            #pragma unroll
            for (int p = 0; p < 2; p++)
                GLD16(W + (size_t)(n0 + p * 64 + ar) * K + k0 + 32 + ac,
                      &Bs[cur ^ 1][(p * 64 + ar) * 32 + ac]);
        }

        bf16x8 af[WMT], bfr[4];
        #pragma unroll
        for (int mt = 0; mt < WMT; mt++)
            af[mt] = *(const bf16x8*)&As[cur][(wm * (WMT * 16) + mt * 16 + l15) * 32 + quad * 8];
        #pragma unroll
        for (int nt = 0; nt < 4; nt++)
            bfr[nt] = *(const bf16x8*)&Bs[cur][(wn * 64 + nt * 16 + l15) * 32 + quad * 8];
        #pragma unroll
        for (int mt = 0; mt < WMT; mt++)
            #pragma unroll
            for (int nt = 0; nt < 4; nt++)
                acc[mt][nt] = __builtin_amdgcn_mfma_f32_16x16x32_bf16(
                    af[mt], bfr[nt], acc[mt][nt], 0, 0, 0);
    }

    // epilogue: C[row][col], row = m0+wm*WMT*16+mt*16+quad*4+r, col = n0+wn*64+nt*16+l15
    if (MODE == 1) {
        #pragma unroll
        for (int mt = 0; mt < WMT; mt++)
            #pragma unroll
            for (int r = 0; r < 4; r++) {
                int row = m0 + wm * (WMT * 16) + mt * 16 + quad * 4 + r;
                #pragma unroll
                for (int nt = 0; nt < 4; nt++) {
                    int col = n0 + wn * 64 + nt * 16 + l15;
                    outf[(size_t)row * N + col] = acc[mt][nt][r] + bias[col];
                }
            }
    } else {
        const int colbase = n0 + wn * 64;          // 64-aligned -> one (which,h)
        const int which   = colbase >> 10;         // 0=q, 1=k, 2=v
        const int hh      = (colbase & (Cc - 1)) >> 6;
        if (which == 2) {
            // V compacted+transposed+swizzled: element (d, c) at
            // head + d*L + (c&~63) + ((((c>>3)&7) ^ (d&7))<<3) + (c&7)
            #pragma unroll
            for (int mt = 0; mt < WMT; mt++)
                #pragma unroll
                for (int r = 0; r < 4; r++) {
                    int row = m0 + wm * (WMT * 16) + mt * 16 + quad * 4 + r;
                    int b = row >> 11, l = row & (Ll - 1);
                    if (cmask[b * Ll + l]) {
                        int c = cidx[b * Ll + l];
                        size_t head = (size_t)(b * Hh + hh) * Dd * Ll;
                        int lbase = (c & ~63) | (c & 7);
                        int lg    = (c >> 3) & 7;
                        #pragma unroll
                        for (int nt = 0; nt < 4; nt++) {
                            int d = nt * 16 + l15;
                            int pos = lbase | ((lg ^ (d & 7)) << 3);
                            vb[head + (size_t)d * Ll + pos] = __float2bfloat16(acc[mt][nt][r]);
                        }
                    }
                }
        } else {
            bf16* dst = which ? kb : qb;
            const float qs = which ? 1.0f : QSCALE;
            const float base0 = __expf(-(float)l15 * INVFREQ_LN);
            const float base1 = __expf(-(float)(l15 + 16) * INVFREQ_LN);
            #pragma unroll
            for (int mt = 0; mt < WMT; mt++)
                #pragma unroll
                for (int r = 0; r < 4; r++) {
                    int row = m0 + wm * (WMT * 16) + mt * 16 + quad * 4 + r;
                    int b = row >> 11, l = row & (Ll - 1);
                    int cm = 1, c = l;
                    if (which == 1) {
                        cm = cmask[b * Ll + l];
                        c  = cidx[b * Ll + l];
                    }
                    if (cm) {
                        size_t rb = ((size_t)(b * Hh + hh) * Ll + c) * Dd;
                        #pragma unroll
                        for (int nt2 = 0; nt2 < 2; nt2++) {
                            float fr = (float)l * (nt2 ? base1 : base0);
                            float sn, cs;
                            __sincosf(fr, &sn, &cs);
                            float x1 = acc[mt][nt2][r];
                            float x2 = acc[mt][nt2 + 2][r];
                            float o1 = (x1 * cs - x2 * sn) * qs;
                            float o2 = (x2 * cs + x1 * sn) * qs;
                            int d1 = nt2 * 16 + l15;
                            int d2 = d1 + 32;
                            if (which == 1) {
                                int sw = c & 7;
                                int a1 = ((((d1 >> 3) ^ sw)) << 3) | (d1 & 7);
                                int a2 = ((((d2 >> 3) ^ sw)) << 3) | (d2 & 7);
                                dst[rb + a1] = __float2bfloat16(o1);
                                dst[rb + a2] = __float2bfloat16(o2);
                            } else {
                                dst[rb + d1] = __float2bfloat16(o1);
                                dst[rb + d2] = __float2bfloat16(o2);
                            }
                        }
                    }
                }
        }
    }
}

// ---------------- Flash attention: compacted keys, GLD16 dbuf, 1 barrier/tile ----------------
// q pre-scaled+roped (linear); k compacted+roped+swizzled; v compacted+transposed+swizzled.
// Tail tile masked by key index (p=0 for key >= nvalid) -> no memset, no pad correction.
// Block = 512 threads = 8 waves; each wave one 16-q subtile (128 q/block).
#define LSTR 72

__global__ __launch_bounds__(512) void attn_mfma(
    const bf16* __restrict__ q, const bf16* __restrict__ k, const bf16* __restrict__ vt,
    const int* __restrict__ valid, bf16* __restrict__ ctx)
{
    __shared__ __align__(16) short Ks[2][64 * 64];
    __shared__ __align__(16) short Vs[2][64 * 64];
    __shared__ __align__(16) short Ps[8][16 * LSTR];

    const int tid  = threadIdx.x;
    const int wave = tid >> 6;
    const int lane = tid & 63;
    const int l15  = lane & 15;
    const int quad = lane >> 4;

    const int bh = blockIdx.x & 31;           // (b*H + h) -> fixed XCD per head
    const int q0 = (blockIdx.x >> 5) << 7;    // 128-query tile start
    const int b  = bh >> 4;
    const int h  = bh & (Hh - 1);

    const int nvalid = valid[b];
    const int ntiles = (nvalid + 63) >> 6;

    const short* qb  = (const short*)(q  + (size_t)bh * Ll * Dd);
    const short* kb  = (const short*)(k  + (size_t)bh * Ll * Dd);
    const short* vtb = (const short*)(vt + (size_t)bh * Dd * Ll);

    // Q fragment: wave's 16 rows (linear layout)
    const int qrow = q0 + wave * 16 + l15;
    bf16x8 qa0 = *(const bf16x8*)(qb + (size_t)qrow * Dd + quad * 8);
    bf16x8 qa1 = *(const bf16x8*)(qb + (size_t)qrow * Dd + 32 + quad * 8);

    // swizzled group offsets (shorts) within a 64-short row, row&7 == l15&7
    const int g0 = ((quad ^ (l15 & 7)) << 3);
    const int g1 = (((quad + 4) ^ (l15 & 7)) << 3);

    // staging pointers: thread covers row tid>>3, group tid&7 of a 64x64 tile
    const short* vgp = vtb + (size_t)(tid >> 3) * Ll + ((tid & 7) << 3);
    short* ksl = &Ks[0][0] + tid * 8;   // lane-linear LDS dest (x8 shorts = 16B)
    short* vsl = &Vs[0][0] + tid * 8;
    const int lbuf = 64 * 64;           // buffer stride in shorts

    floatx4 O[4];
    float l_r = 0.f;
    #pragma unroll
    for (int nt = 0; nt < 4; nt++)
        #pragma unroll
        for (int r = 0; r < 4; r++) O[nt][r] = 0.f;

    // prologue: stage tile 0 into buffer 0
    GLD16(kb + tid * 8, ksl);
    GLD16(vgp, vsl);

    for (int t = 0; t < ntiles; t++) {
        const int cur = t & 1;
        __syncthreads();   // drains this tile's GLDs (vmcnt)
        if (t + 1 < ntiles) {
            const int s1 = (t + 1) << 6;
            GLD16(kb + (size_t)s1 * Dd + tid * 8, ksl + (cur ^ 1) * lbuf);
            GLD16(vgp + s1,                       vsl + (cur ^ 1) * lbuf);
        }

        // ---- S^T = K Q^T: lane holds S[q=l15][key=nt*16+quad*4+r] ----
        const short* Kc = &Ks[cur][0];
        const short* Vc = &Vs[cur][0];
        floatx4 S[4];
        #pragma unroll
        for (int nt = 0; nt < 4; nt++) {
            const short* krow = Kc + (nt * 16 + l15) * 64;
            bf16x8 ka0 = *(const bf16x8*)(krow + g0);
            bf16x8 ka1 = *(const bf16x8*)(krow + g1);
            floatx4 acc; acc[0] = acc[1] = acc[2] = acc[3] = 0.f;
            acc = __builtin_amdgcn_mfma_f32_16x16x32_bf16(ka0, qa0, acc, 0, 0, 0);
            acc = __builtin_amdgcn_mfma_f32_16x16x32_bf16(ka1, qa1, acc, 0, 0, 0);
            S[nt] = acc;
        }

        // ---- softmax: p = exp(S); tail tile masks key >= nvalid ----
        if (t + 1 < ntiles) {
            #pragma unroll
            for (int nt = 0; nt < 4; nt++) {
                bf16x4 pw;
                #pragma unroll
                for (int r = 0; r < 4; r++) {
                    float p = __expf(S[nt][r]);
                    l_r += p;
                    pw[r] = f2bf_rn(p);
                }
                *(bf16x4*)&Ps[wave][l15 * LSTR + nt * 16 + quad * 4] = pw;
            }
        } else {
            const int kbase = (t << 6) + quad * 4;
            #pragma unroll
            for (int nt = 0; nt < 4; nt++) {
                bf16x4 pw;
                #pragma unroll
                for (int r = 0; r < 4; r++) {
                    float p = (kbase + nt * 16 + r < nvalid) ? __expf(S[nt][r]) : 0.f;
                    l_r += p;
                    pw[r] = f2bf_rn(p);
                }
                *(bf16x4*)&Ps[wave][l15 * LSTR + nt * 16 + quad * 4] = pw;
            }
        }

        // ---- O^T += V^T P^T: A=Vs rows (d, swizzled), B=Ps rows (q) ----
        bf16x8 pb0 = *(const bf16x8*)&Ps[wave][l15 * LSTR + quad * 8];
        bf16x8 pb1 = *(const bf16x8*)&Ps[wave][l15 * LSTR + 32 + quad * 8];
        #pragma unroll
        for (int nt = 0; nt < 4; nt++) {
            const short* vrow = Vc + (nt * 16 + l15) * 64;
            bf16x8 va0 = *(const bf16x8*)(vrow + g0);
            bf16x8 va1 = *(const bf16x8*)(vrow + g1);
            O[nt] = __builtin_amdgcn_mfma_f32_16x16x32_bf16(va0, pb0, O[nt], 0, 0, 0);
            O[nt] = __builtin_amdgcn_mfma_f32_16x16x32_bf16(va1, pb1, O[nt], 0, 0, 0);
        }
    }

    // ---- row-sum (quads hold same q) ----
    float l = l_r;
    l += __shfl_xor(l, 16);
    l += __shfl_xor(l, 32);
    const float inv = 1.0f / l;

    // ---- write ctx: lane holds O[q=l15][d=nt*16+quad*4+r] -> b64 stores ----
    {
        int row = q0 + wave * 16 + l15;
        short* cp = (short*)ctx + ((size_t)(b * Ll + row)) * Cc + h * Dd;
        #pragma unroll
        for (int nt = 0; nt < 4; nt++) {
            bf16x4 ov;
            #pragma unroll
            for (int r = 0; r < 4; r++) ov[r] = f2bf_rn(O[nt][r] * inv);
            *(bf16x4*)&cp[nt * 16 + quad * 4] = ov;
        }
    }
}

extern "C" void kernel_launch(void* const* d_in, const int* in_sizes, int n_in,
                              void* d_out, int out_size, void* d_ws, size_t ws_size,
                              hipStream_t stream) {
    const float* x    = (const float*)d_in[0];
    const int*   mask = (const int*)d_in[1];
    const float* Wq   = (const float*)d_in[2];
    const float* Wk   = (const float*)d_in[3];
    const float* Wv   = (const float*)d_in[4];
    const float* Wo   = (const float*)d_in[5];
    const float* bo   = (const float*)d_in[6];
    float* out = (float*)d_out;

    const size_t per = (size_t)Bb * Hh * Ll * Dd;   // 4 Mi elements
    bf16* qbuf = (bf16*)d_ws;
    bf16* kbuf = qbuf + per;            // compacted + swizzled
    bf16* vbuf = kbuf + per;            // compacted + transposed [B,H,D,L'] + swizzled
    bf16* xb   = vbuf + per;            // also used as ctx after x is dead
    bf16* wqkv = xb + per;              // [3072, 1024]
    bf16* wob  = wqkv + (size_t)3 * Cc * Cc;
    int*  cidx   = (int*)(wob + (size_t)Cc * Cc);
    int*  cvalid = cidx + Bb * Ll;
    bf16* ctx  = xb;

    const int M = Bb * Ll;   // 4096

    convert_scan<<<NCONV + Bb, 256, 0, stream>>>(
        x, Wq, Wk, Wv, Wo, xb, wqkv, wob, mask, cidx, cvalid);

    // fused QKV projection + RoPE + Q-scale + K/V compaction/swizzle + V-transpose
    // 256x128 blocks (wave tile 128x64) to cut LDS traffic per FLOP
    dim3 gQKV(3 * Cc / 128, M / 256);
    gemm_mfma<0, 8><<<gQKV, 256, 0, stream>>>(xb, wqkv, qbuf, kbuf, vbuf,
                                              nullptr, nullptr, mask, cidx, M, 3 * Cc, Cc);

    attn_mfma<<<Bb * Hh * (Ll / 128), 512, 0, stream>>>(qbuf, kbuf, vbuf, cvalid, ctx);

    // output projection: [4096, 1024] fp32 + bias (128x128 blocks: 256 blocks = 1/CU)
    dim3 gOut(Cc / 128, M / 128);
    gemm_mfma<1, 4><<<gOut, 256, 0, stream>>>(ctx, wob, nullptr, nullptr, nullptr,
                                              out, bo, nullptr, nullptr, M, Cc, Cc);
}